// Round 3
// baseline (309.843 us; speedup 1.0000x reference)
//
#include <hip/hip_runtime.h>

#define DD 512
#define AA 128
#define BB 1024

typedef float f4 __attribute__((ext_vector_type(4)));

// k1: per-block partial column sums of attribute [BB, DD].
// 128 blocks x 256 threads; block b sums rows b*8 .. b*8+7 into partial[b][512].
__global__ void k_partial(const float* __restrict__ attr, float* __restrict__ partial) {
    const int r0 = blockIdx.x * 8;
    const int t  = threadIdx.x;
    float s0 = 0.0f, s1 = 0.0f;
    #pragma unroll
    for (int r = 0; r < 8; ++r) {
        const float* row = attr + (size_t)(r0 + r) * DD;
        s0 += row[t];
        s1 += row[t + 256];
    }
    float* dst = partial + (size_t)blockIdx.x * DD;
    dst[t]       = s0;
    dst[t + 256] = s1;
}

// k2: fused reduce + GEMV1. 128 blocks x 256 threads.
// Each block redundantly reduces partial[128][512] -> colsum in LDS (coalesced,
// 256 KB/block, L2/L3-resident), then its 4 waves compute 4 rows of vbar.
__global__ void k_redgemv(const float* __restrict__ partial,
                          const float* __restrict__ Wv, const float* __restrict__ bv,
                          float* __restrict__ vbar) {
    __shared__ float cs[DD];
    const int t = threadIdx.x;
    float s0 = 0.0f, s1 = 0.0f;
    #pragma unroll 4
    for (int i = 0; i < 128; ++i) {
        const float* p = partial + (size_t)i * DD;
        s0 += p[t];
        s1 += p[t + 256];
    }
    cs[t]       = s0;
    cs[t + 256] = s1;
    __syncthreads();
    const int wave = t >> 6, lane = t & 63;
    const int d = blockIdx.x * 4 + wave;           // 0..511
    const float* wr = Wv + (size_t)d * DD;
    float s = 0.0f;
    #pragma unroll
    for (int e = lane; e < DD; e += 64) s += cs[e] * wr[e];
    #pragma unroll
    for (int off = 32; off > 0; off >>= 1) s += __shfl_down(s, off, 64);
    if (lane == 0) vbar[d] = s * (1.0f / (float)BB) + bv[d];
}

// k3: GEMV2: ovec[d] = sum_e vbar[e]*Wo[d][e] + bo[d]. One wave per row.
__global__ void k_gemv2(const float* __restrict__ Wo, const float* __restrict__ bo,
                        const float* __restrict__ vbar, float* __restrict__ ovec) {
    const int wave = threadIdx.x >> 6, lane = threadIdx.x & 63;
    const int d = blockIdx.x * 4 + wave;           // 0..511
    const float* wr = Wo + (size_t)d * DD;
    float s = 0.0f;
    #pragma unroll
    for (int e = lane; e < DD; e += 64) s += vbar[e] * wr[e];
    #pragma unroll
    for (int off = 32; off > 0; off >>= 1) s += __shfl_down(s, off, 64);
    if (lane == 0) ovec[d] = s + bo[d];
}

// k4: broadcast ovec[512] to out [BB*AA*DD] with nontemporal float4 streams.
// Grid stride 524288 is a multiple of 128 float4/row -> per-thread source is
// loop-invariant (one register).
__global__ void k_bcast(const float* __restrict__ o, f4* __restrict__ out, long total4) {
    long idx = (long)blockIdx.x * blockDim.x + threadIdx.x;
    const long step = (long)gridDim.x * blockDim.x;   // 2048*256 = 524288
    const f4 v = ((const f4*)o)[idx & 127];
    for (; idx < total4; idx += step)
        __builtin_nontemporal_store(v, out + idx);
}

extern "C" void kernel_launch(void* const* d_in, const int* in_sizes, int n_in,
                              void* d_out, int out_size, void* d_ws, size_t ws_size,
                              hipStream_t stream) {
    // setup_inputs order: attribute, prompt, Wq, bq, Wk, bk, Wv, bv, Wo, bo
    const float* attr = (const float*)d_in[0];
    const float* Wv   = (const float*)d_in[6];
    const float* bv   = (const float*)d_in[7];
    const float* Wo   = (const float*)d_in[8];
    const float* bo   = (const float*)d_in[9];

    float* ws      = (float*)d_ws;
    float* partial = ws;                 // [128*512]
    float* vbar    = ws + 128 * DD;      // [512]
    float* ovec    = vbar + DD;          // [512]
    float* out     = (float*)d_out;

    k_partial<<<128, 256, 0, stream>>>(attr, partial);
    k_redgemv<<<128, 256, 0, stream>>>(partial, Wv, bv, vbar);
    k_gemv2  <<<128, 256, 0, stream>>>(Wo, bo, vbar, ovec);

    const long total4 = (long)BB * AA * (DD / 4);     // 16,777,216 float4
    k_bcast  <<<2048, 256, 0, stream>>>(ovec, (f4*)out, total4);
}

// Round 5
// 298.643 us; speedup vs baseline: 1.0375x; 1.0375x over previous
//
#include <hip/hip_runtime.h>

#define DD 512
#define AA 128
#define BB 1024

typedef float f4 __attribute__((ext_vector_type(4)));

// k1: per-block partial column sums of attribute [BB, DD].
// 128 blocks x 256 threads; block b sums rows b*8 .. b*8+7 into partial[b][512].
__global__ void k_partial(const float* __restrict__ attr, float* __restrict__ partial) {
    const int r0 = blockIdx.x * 8;
    const int t  = threadIdx.x;
    float s0 = 0.0f, s1 = 0.0f;
    #pragma unroll
    for (int r = 0; r < 8; ++r) {
        const float* row = attr + (size_t)(r0 + r) * DD;
        s0 += row[t];
        s1 += row[t + 256];
    }
    float* dst = partial + (size_t)blockIdx.x * DD;
    dst[t]       = s0;
    dst[t + 256] = s1;
}

// k2: fused reduce + GEMV1. 128 blocks x 256 threads.
// Each block redundantly reduces partial[128][512] -> colsum in LDS (coalesced,
// 256 KB/block, L2/L3-resident), then its 4 waves compute 4 rows of vbar.
__global__ void k_redgemv(const float* __restrict__ partial,
                          const float* __restrict__ Wv, const float* __restrict__ bv,
                          float* __restrict__ vbar) {
    __shared__ float cs[DD];
    const int t = threadIdx.x;
    float s0 = 0.0f, s1 = 0.0f;
    #pragma unroll 4
    for (int i = 0; i < 128; ++i) {
        const float* p = partial + (size_t)i * DD;
        s0 += p[t];
        s1 += p[t + 256];
    }
    cs[t]       = s0;
    cs[t + 256] = s1;
    __syncthreads();
    const int wave = t >> 6, lane = t & 63;
    const int d = blockIdx.x * 4 + wave;           // 0..511
    const float* wr = Wv + (size_t)d * DD;
    float s = 0.0f;
    #pragma unroll
    for (int e = lane; e < DD; e += 64) s += cs[e] * wr[e];
    #pragma unroll
    for (int off = 32; off > 0; off >>= 1) s += __shfl_down(s, off, 64);
    if (lane == 0) vbar[d] = s * (1.0f / (float)BB) + bv[d];
}

// k3: GEMV2: ovec[d] = sum_e vbar[e]*Wo[d][e] + bo[d]. One wave per row.
__global__ void k_gemv2(const float* __restrict__ Wo, const float* __restrict__ bo,
                        const float* __restrict__ vbar, float* __restrict__ ovec) {
    const int wave = threadIdx.x >> 6, lane = threadIdx.x & 63;
    const int d = blockIdx.x * 4 + wave;           // 0..511
    const float* wr = Wo + (size_t)d * DD;
    float s = 0.0f;
    #pragma unroll
    for (int e = lane; e < DD; e += 64) s += vbar[e] * wr[e];
    #pragma unroll
    for (int off = 32; off > 0; off >>= 1) s += __shfl_down(s, off, 64);
    if (lane == 0) ovec[d] = s + bo[d];
}

// k4: broadcast ovec[512] to out [BB*AA*DD]; PLAIN float4 stores (NT store was
// a measured -15us regression in R3 -- L2 write path beats direct-to-HBM here).
// Grid stride 524288 is a multiple of 128 float4/row -> per-thread source is
// loop-invariant (one register).
__global__ void k_bcast(const float* __restrict__ o, f4* __restrict__ out, long total4) {
    long idx = (long)blockIdx.x * blockDim.x + threadIdx.x;
    const long step = (long)gridDim.x * blockDim.x;   // 2048*256 = 524288
    const f4 v = ((const f4*)o)[idx & 127];
    for (; idx < total4; idx += step)
        out[idx] = v;
}

extern "C" void kernel_launch(void* const* d_in, const int* in_sizes, int n_in,
                              void* d_out, int out_size, void* d_ws, size_t ws_size,
                              hipStream_t stream) {
    // setup_inputs order: attribute, prompt, Wq, bq, Wk, bk, Wv, bv, Wo, bo
    const float* attr = (const float*)d_in[0];
    const float* Wv   = (const float*)d_in[6];
    const float* bv   = (const float*)d_in[7];
    const float* Wo   = (const float*)d_in[8];
    const float* bo   = (const float*)d_in[9];

    float* ws      = (float*)d_ws;
    float* partial = ws;                 // [128*512]
    float* vbar    = ws + 128 * DD;      // [512]
    float* ovec    = vbar + DD;          // [512]
    float* out     = (float*)d_out;

    k_partial<<<128, 256, 0, stream>>>(attr, partial);
    k_redgemv<<<128, 256, 0, stream>>>(partial, Wv, bv, vbar);
    k_gemv2  <<<128, 256, 0, stream>>>(Wo, bo, vbar, ovec);

    const long total4 = (long)BB * AA * (DD / 4);     // 16,777,216 float4
    k_bcast  <<<2048, 256, 0, stream>>>(ovec, (f4*)out, total4);
}